// Round 9
// baseline (897.079 us; speedup 1.0000x reference)
//
#include <hip/hip_runtime.h>

typedef __attribute__((ext_vector_type(8))) short bfrag8;   // 8 x bf16 (4 VGPRs)
typedef __attribute__((ext_vector_type(4))) float f32x4;    // MFMA accumulator

typedef const unsigned int __attribute__((address_space(1)))* gas1_u32;
typedef unsigned int __attribute__((address_space(3)))* gas3_u32;

#define DEV __device__ __forceinline__

DEV unsigned short f2bf(float f) {              // f32 -> bf16 bits, RNE
  unsigned int u = __builtin_bit_cast(unsigned int, f);
  u += 0x7fffu + ((u >> 16) & 1u);
  return (unsigned short)(u >> 16);
}

DEV void gload_lds16(const void* g, void* l) {  // async global->LDS, 16B/lane
  __builtin_amdgcn_global_load_lds((gas1_u32)g, (gas3_u32)l, 16, 0, 0);
}

// counted-wait + barrier; "memory" clobber fences reordering across the gate
template<int N> DEV void gate_bar();
template<> DEV void gate_bar<6>() { asm volatile("s_waitcnt vmcnt(6)\n\ts_barrier" ::: "memory"); }
template<> DEV void gate_bar<8>() { asm volatile("s_waitcnt vmcnt(8)\n\ts_barrier" ::: "memory"); }

// ---------------- full LN of latents -> bf16 (block per row of 2048) ---------------
__global__ __launch_bounds__(256) void k_lnlat(
    const float* __restrict__ lat, const float* __restrict__ w,
    const float* __restrict__ b, unsigned short* __restrict__ ln)
{
  const int row = blockIdx.x, tid = threadIdx.x;
  const float* base = lat + (size_t)row * 2048;
  const float4 v0 = ((const float4*)base)[tid];
  const float4 v1 = ((const float4*)base)[256 + tid];
  float s = v0.x+v0.y+v0.z+v0.w + v1.x+v1.y+v1.z+v1.w;
  float q = v0.x*v0.x+v0.y*v0.y+v0.z*v0.z+v0.w*v0.w
          + v1.x*v1.x+v1.y*v1.y+v1.z*v1.z+v1.w*v1.w;
  #pragma unroll
  for (int off = 32; off >= 1; off >>= 1) { s += __shfl_xor(s, off); q += __shfl_xor(q, off); }
  __shared__ float red[8];
  const int wid = tid >> 6, lane = tid & 63;
  if (lane == 0) { red[wid] = s; red[4 + wid] = q; }
  __syncthreads();
  s = red[0] + red[1] + red[2] + red[3];
  q = red[4] + red[5] + red[6] + red[7];
  const float m  = s * (1.0f/2048.0f);
  const float var = q * (1.0f/2048.0f) - m * m;
  const float rs = rsqrtf(var + 1e-5f);
  const float4 w0 = ((const float4*)w)[tid], w1 = ((const float4*)w)[256 + tid];
  const float4 b0 = ((const float4*)b)[tid], b1 = ((const float4*)b)[256 + tid];
  ushort4 o0, o1;
  o0.x = f2bf((v0.x - m) * rs * w0.x + b0.x);
  o0.y = f2bf((v0.y - m) * rs * w0.y + b0.y);
  o0.z = f2bf((v0.z - m) * rs * w0.z + b0.z);
  o0.w = f2bf((v0.w - m) * rs * w0.w + b0.w);
  o1.x = f2bf((v1.x - m) * rs * w1.x + b1.x);
  o1.y = f2bf((v1.y - m) * rs * w1.y + b1.y);
  o1.z = f2bf((v1.z - m) * rs * w1.z + b1.z);
  o1.w = f2bf((v1.w - m) * rs * w1.w + b1.w);
  ((ushort4*)(ln + (size_t)row * 2048))[tid] = o0;
  ((ushort4*)(ln + (size_t)row * 2048))[256 + tid] = o1;
}

// ---------------- tiled transpose + bf16 cast: src[K][N] f32 -> dst[N][K] bf16 --------
__global__ __launch_bounds__(256) void k_transpose_cast(
    const float* __restrict__ src, unsigned short* __restrict__ dst,
    int K, int N, const float* __restrict__ rowscale, float scale)
{
  __shared__ float tile[32][33];
  const int tx = threadIdx.x & 31, ty = threadIdx.x >> 5;
  const int ntiles = N >> 5;
  const int k0 = (blockIdx.x / ntiles) << 5;
  const int n0 = (blockIdx.x % ntiles) << 5;
  #pragma unroll
  for (int r = 0; r < 4; ++r) {
    const int kk = ty + r * 8;
    float v = src[(size_t)(k0 + kk) * N + n0 + tx] * scale;
    if (rowscale) v *= rowscale[k0 + kk];
    tile[kk][tx] = v;
  }
  __syncthreads();
  #pragma unroll
  for (int r = 0; r < 4; ++r) {
    const int nn = ty + r * 8;
    dst[(size_t)(n0 + nn) * K + k0 + tx] = f2bf(tile[tx][nn]);
  }
}

// ---------------- c1/c2 two-stage deterministic reduce -------------------------------
__global__ __launch_bounds__(256) void k_c1c2_part(
    const float* __restrict__ Wkv, const float* __restrict__ w,
    const float* __restrict__ b, float* __restrict__ part)
{
  const int kc = blockIdx.x;                 // 16 chunks of 64 k-rows
  const int n  = blockIdx.y * 256 + threadIdx.x;
  float s1 = 0.f, s2 = 0.f;
  const int k0 = kc * 64;
  for (int k = k0; k < k0 + 64; ++k) {
    const float wv = Wkv[(size_t)k * 1024 + n];
    s1 += w[k] * wv;
    s2 += b[k] * wv;
  }
  part[(size_t)(kc * 2 + 0) * 1024 + n] = s1;
  part[(size_t)(kc * 2 + 1) * 1024 + n] = s2;
}

__global__ __launch_bounds__(256) void k_c1c2_red(
    const float* __restrict__ part, float* __restrict__ c1, float* __restrict__ c2)
{
  const int n = blockIdx.x * 256 + threadIdx.x;
  float s1 = 0.f, s2 = 0.f;
  #pragma unroll
  for (int kc = 0; kc < 16; ++kc) {
    s1 += part[(size_t)(kc * 2 + 0) * 1024 + n];
    s2 += part[(size_t)(kc * 2 + 1) * 1024 + n];
  }
  c1[n] = s1; c2[n] = s2;
}

// =====================================================================================
// kv GEMM with FUSED x-stats: C[65536x1024] = LN(x) @ Wkv^T, reading x as f32 directly.
// R6 4-phase/8-wave/256^2 core for B (gload_lds) + MFMA, unchanged. A is reg-staged:
// thread owns row tid>>1, k-slice (tid&1)*16 per kk-half; per tile: 8x dwordx4 f32
// loads (phase A) -> f2bf cvt + 2x2 ds_write_b128 (phases B,C) into the NEXT buffer,
// accumulating per-thread sum/sumsq. After the K loop: __shfl_xor(1) pair-reduce ->
// per-row mu/rstd in 2KB LDS -> epilogue. No xb buffer, no k_xstats pass.
// A-write placement reproduces R6's read swizzle: logical slot L at physical
// (L + rho)&3, rho=(row>>1)&3 -> rdA/rdB/MFMA identical to R6.
// Gates (robust to intra-phase reorder; phases are asm-fenced):
//  per tile VMEM = [ax x8, Bkk0 x2]_A [Bkk1 x2]_B; ax drained by putA consumption.
//  GATE_A = vmcnt(10): drains previous tile's Bkk1 (oldest 2 of <=12) before phase B
//  reads it. GATE_D = vmcnt(2)+lgkmcnt(0): drains Bkk0 (next tile phase A reads) and
//  all ds_writes; leaves Bkk1 x2 in flight. Wrap tile stages with accum=false so
//  stats count each tile exactly once. ds_write->ds_read separations >= 2 barriers.
// =====================================================================================
__global__ __launch_bounds__(512, 2) void k_gemm8f(
    const float* __restrict__ X,             // f32 [65536][1024]
    const unsigned short* __restrict__ Bt,   // WkvT bf16 [1024][1024]
    unsigned short* __restrict__ C,          // kv bf16 [65536][1024]
    const float* __restrict__ c1, const float* __restrict__ c2)
{
  constexpr int NKT = 16;                     // K=1024 / BK=64
  __shared__ __attribute__((aligned(16))) char lds[131072];
  __shared__ float sstat[256][2];             // per-row mu, rstd

  int bid = blockIdx.x;
  { const int nwg = gridDim.x; const int q = nwg >> 3; bid = (bid & 7) * q + (bid >> 3); }
  const int mt = bid >> 2, nt = bid & 3;      // nt fastest: 4 blocks share A panel
  const int tid = threadIdx.x;
  const int wid = tid >> 6, lane = tid & 63;
  const int g = lane >> 4, c = lane & 15;
  const int wr = wid >> 2, wc = wid & 3;
  const int MO = wr * 128, NO = wc * 64;

  const unsigned short* gB = Bt + (size_t)nt * 256 * 1024;
  // A ownership: row arow = tid>>1 (of 256), k-slice (tid&1)*16 per kk-half
  const int arow = tid >> 1, asl = tid & 1;
  const int rho = (arow >> 1) & 3;
  const int ps0 = (2 * asl + 0 + rho) & 3;    // physical 16B slots for this thread
  const int ps1 = (2 * asl + 1 + rho) & 3;
  const float* gX = X + (size_t)(mt * 256 + arow) * 1024 + asl * 16;

  const f32x4 zz = {0.f, 0.f, 0.f, 0.f};
  f32x4 acc[8][4];
  #pragma unroll
  for (int m = 0; m < 8; ++m)
    #pragma unroll
    for (int n = 0; n < 4; ++n) acc[m][n] = zz;

  float4 ax[2][4];                            // next A tile, f32 (32 VGPRs)
  float ssum = 0.f, sq = 0.f;                 // per-thread stats partials

  auto loadA = [&](int kt) {
    #pragma unroll
    for (int kk = 0; kk < 2; ++kk)
      #pragma unroll
      for (int i = 0; i < 4; ++i)
        ax[kk][i] = *(const float4*)(gX + (size_t)kt * 64 + kk * 32 + i * 4);
  };
  auto putA = [&](int buf, int kk, int accum) {
    unsigned int w[8];
    #pragma unroll
    for (int i = 0; i < 4; ++i) {
      const float4 v = ax[kk][i];
      if (accum) {
        ssum += v.x + v.y + v.z + v.w;
        sq   += v.x*v.x + v.y*v.y + v.z*v.z + v.w*v.w;
      }
      w[2*i]   = (unsigned)f2bf(v.x) | ((unsigned)f2bf(v.y) << 16);
      w[2*i+1] = (unsigned)f2bf(v.z) | ((unsigned)f2bf(v.w) << 16);
    }
    char* base = lds + buf * 32768 + kk * 16384 + arow * 64;
    *(uint4*)(base + ps0 * 16) = make_uint4(w[0], w[1], w[2], w[3]);
    *(uint4*)(base + ps1 * 16) = make_uint4(w[4], w[5], w[6], w[7]);
  };
  auto stageB = [&](int buf, int kk, int kt) {
    #pragma unroll
    for (int i = 0; i < 2; ++i) {
      const int o = (i * 512 + tid) * 16;
      const int row = o >> 6;
      const int ss = ((((o >> 4) & 3) - (row >> 1)) & 3);
      gload_lds16((const char*)(gB + (size_t)row * 1024 + kt * 64 + kk * 32) + ss * 16,
                  lds + 65536 + buf * 32768 + kk * 16384 + o);
    }
  };
  auto rdA = [&](int buf, int kk, int m) -> bfrag8 {
    const int row = MO + m * 16 + c;
    return *(const bfrag8*)(lds + buf * 32768 + kk * 16384 + row * 64
                            + (((g + (row >> 1)) & 3) << 4));
  };
  auto rdB = [&](int buf, int kk, int n) -> bfrag8 {
    const int row = NO + n * 16 + c;
    return *(const bfrag8*)(lds + 65536 + buf * 32768 + kk * 16384 + row * 64
                            + (((g + (row >> 1)) & 3) << 4));
  };

  bfrag8 a[8], b0[4], b1[4];

  // one K-tile = 4 phases; computes buf, stages tile ukt into sb
  auto tile4 = [&](int buf, int sb, int ukt, int accum) {
    // phase A: ds_read a(kk0), b(kk0); issue A f32 loads + B kk0 DMA
    #pragma unroll
    for (int m = 0; m < 8; ++m) a[m] = rdA(buf, 0, m);
    #pragma unroll
    for (int n = 0; n < 4; ++n) b0[n] = rdB(buf, 0, n);
    loadA(ukt);
    stageB(sb, 0, ukt);
    __builtin_amdgcn_s_setprio(1);
    #pragma unroll
    for (int m = 0; m < 8; ++m) {
      acc[m][0] = __builtin_amdgcn_mfma_f32_16x16x32_bf16(a[m], b0[0], acc[m][0], 0, 0, 0);
      acc[m][1] = __builtin_amdgcn_mfma_f32_16x16x32_bf16(a[m], b0[1], acc[m][1], 0, 0, 0);
    }
    __builtin_amdgcn_s_setprio(0);
    asm volatile("s_waitcnt vmcnt(10)\n\ts_barrier" ::: "memory");   // lands prev Bkk1
    // phase B: ds_read b(kk1); cvt+write A kk0 -> sb; B kk1 DMA
    #pragma unroll
    for (int n = 0; n < 4; ++n) b1[n] = rdB(buf, 1, n);
    putA(sb, 0, accum);
    stageB(sb, 1, ukt);
    __builtin_amdgcn_s_setprio(1);
    #pragma unroll
    for (int m = 0; m < 8; ++m) {
      acc[m][2] = __builtin_amdgcn_mfma_f32_16x16x32_bf16(a[m], b0[2], acc[m][2], 0, 0, 0);
      acc[m][3] = __builtin_amdgcn_mfma_f32_16x16x32_bf16(a[m], b0[3], acc[m][3], 0, 0, 0);
    }
    __builtin_amdgcn_s_setprio(0);
    asm volatile("s_barrier" ::: "memory");
    // phase C: ds_read a(kk1); cvt+write A kk1 -> sb
    #pragma unroll
    for (int m = 0; m < 8; ++m) a[m] = rdA(buf, 1, m);
    putA(sb, 1, accum);
    __builtin_amdgcn_s_setprio(1);
    #pragma unroll
    for (int m = 0; m < 8; ++m) {
      acc[m][0] = __builtin_amdgcn_mfma_f32_16x16x32_bf16(a[m], b1[0], acc[m][0], 0, 0, 0);
      acc[m][1] = __builtin_amdgcn_mfma_f32_16x16x32_bf16(a[m], b1[1], acc[m][1], 0, 0, 0);
    }
    __builtin_amdgcn_s_setprio(0);
    asm volatile("s_barrier" ::: "memory");
    // phase D
    __builtin_amdgcn_s_setprio(1);
    #pragma unroll
    for (int m = 0; m < 8; ++m) {
      acc[m][2] = __builtin_amdgcn_mfma_f32_16x16x32_bf16(a[m], b1[2], acc[m][2], 0, 0, 0);
      acc[m][3] = __builtin_amdgcn_mfma_f32_16x16x32_bf16(a[m], b1[3], acc[m][3], 0, 0, 0);
    }
    __builtin_amdgcn_s_setprio(0);
    asm volatile("s_waitcnt vmcnt(2) lgkmcnt(0)\n\ts_barrier" ::: "memory");  // lands Bkk0 + ds_writes
  };

  // prologue: tile 0 fully into buf0 (A via reg path, B via DMA), full drain
  loadA(0);
  putA(0, 0, 1); putA(0, 1, 1);
  stageB(0, 0, 0); stageB(0, 1, 0);
  asm volatile("s_waitcnt vmcnt(0) lgkmcnt(0)\n\ts_barrier" ::: "memory");

  for (int t = 0; t < NKT; ++t) {
    const int real = (t + 1 < NKT);
    tile4(t & 1, (t & 1) ^ 1, real ? t + 1 : 0, real);  // wrap tile: accum=false
  }
  asm volatile("s_waitcnt vmcnt(0) lgkmcnt(0)" ::: "memory");

  // stats: pair-reduce (tid, tid^1 share row arow) -> LDS
  ssum += __shfl_xor(ssum, 1);
  sq   += __shfl_xor(sq, 1);
  if (asl == 0) {
    const float m = ssum * (1.0f / 1024.0f);
    const float var = sq * (1.0f / 1024.0f) - m * m;
    sstat[arow][0] = m;
    sstat[arow][1] = rsqrtf(var + 1e-5f);
  }
  __syncthreads();

  // epilogue: kv = rstd*(acc - mu*c1) + c2 -> bf16
  #pragma unroll
  for (int m = 0; m < 8; ++m) {
    #pragma unroll
    for (int j = 0; j < 4; ++j) {
      const int rl = MO + m * 16 + g * 4 + j;
      const size_t orow = (size_t)mt * 256 + rl;
      const float muv = sstat[rl][0], rs = sstat[rl][1];
      #pragma unroll
      for (int n = 0; n < 4; ++n) {
        const int gcol = nt * 256 + NO + n * 16 + c;
        const float v = rs * (acc[m][n][j] - muv * c1[gcol]) + c2[gcol];
        C[orow * 1024 + gcol] = f2bf(v);
      }
    }
  }
}

// ---------------- pipelined GEMM (q / out): 4 LDS regions, BK=32 ----------------------
// Gate is vmcnt(2*LPS): depth-3 prefetch keeps 3 stages outstanding; draining to 2*LPS
// lands exactly the oldest stage.
// MODE 1: plain -> bf16        MODE 2: plain -> f32
template<int BM, int BN, int WM, int WN, int NT, int MODE>
__global__ __launch_bounds__(NT, 2) void k_gemm(
    const unsigned short* __restrict__ A, int lda,
    const unsigned short* __restrict__ Bt, int ldb,
    int K, int mtiles, int ntiles,
    void* __restrict__ Cout, int ldc)
{
  constexpr int BK = 32;
  constexpr int NW = NT / 64;
  constexpr int MF = (BM / WM) / 16;
  constexpr int NF = (BN / WN) / 16;
  constexpr int LA = (BM * BK) / (8 * NT);
  constexpr int LB = (BN * BK) / (8 * NT);
  constexpr int LPS = LA + LB;               // loads per stage
  constexpr int RA = BM * BK;
  constexpr int RB = BN * BK;
  static_assert(WM * WN == NW, "wave grid");
  static_assert(LA >= 1 && LB >= 1, "tile too small for NT");
  static_assert(LPS == 3 || LPS == 4, "gate specialization");

  __shared__ __attribute__((aligned(16))) unsigned short As[4 * RA];
  __shared__ __attribute__((aligned(16))) unsigned short Bs[4 * RB];

  int bid = blockIdx.x;
  {
    const int nwg = gridDim.x;
    if ((nwg & 7) == 0) {
      const int q = nwg >> 3;
      bid = (bid & 7) * q + (bid >> 3);
    }
  }
  const int mt = bid / ntiles, nt = bid % ntiles;
  const int tid = threadIdx.x;
  const int wid = tid >> 6, lane = tid & 63;
  const int g = lane >> 4, c = lane & 15;
  const int wr = wid / WN, wc = wid % WN;
  const int MO = wr * (BM / WM), NO = wc * (BN / WN);
  const int rot = (c >> 1) & 3;

  const unsigned short* gA = A + (size_t)mt * BM * lda;
  const unsigned short* gB = Bt + (size_t)nt * BN * ldb;

  const f32x4 zz = {0.f, 0.f, 0.f, 0.f};
  f32x4 acc[MF][NF];
  #pragma unroll
  for (int m = 0; m < MF; ++m)
    #pragma unroll
    for (int n = 0; n < NF; ++n) acc[m][n] = zz;

  auto stage = [&](int R, int kt) {
    #pragma unroll
    for (int i = 0; i < LA; ++i) {
      const int o = (i * NT + tid) * 16;
      const int row = o >> 6;
      const int slot = (o >> 4) & 3;
      const int srcb = (((slot - ((row >> 1) & 3)) & 3) << 4);
      gload_lds16((const char*)(gA + (size_t)row * lda + kt * BK) + srcb,
                  (char*)(As + R * RA) + o);
    }
    #pragma unroll
    for (int i = 0; i < LB; ++i) {
      const int o = (i * NT + tid) * 16;
      const int row = o >> 6;
      const int slot = (o >> 4) & 3;
      const int srcb = (((slot - ((row >> 1) & 3)) & 3) << 4);
      gload_lds16((const char*)(gB + (size_t)row * ldb + kt * BK) + srcb,
                  (char*)(Bs + R * RB) + o);
    }
  };

  auto compute = [&](int R) {
    const char* as = (const char*)(As + R * RA);
    const char* bs = (const char*)(Bs + R * RB);
    bfrag8 af[MF], bf[NF];
    #pragma unroll
    for (int m = 0; m < MF; ++m) {
      const int rw = MO + m * 16 + c;
      af[m] = *(const bfrag8*)(as + rw * 64 + (((g + rot) & 3) << 4));
    }
    #pragma unroll
    for (int n = 0; n < NF; ++n) {
      const int rw = NO + n * 16 + c;
      bf[n] = *(const bfrag8*)(bs + rw * 64 + (((g + rot) & 3) << 4));
    }
    #pragma unroll
    for (int m = 0; m < MF; ++m)
      #pragma unroll
      for (int n = 0; n < NF; ++n)
        acc[m][n] = __builtin_amdgcn_mfma_f32_16x16x32_bf16(af[m], bf[n], acc[m][n], 0, 0, 0);
  };

  const int nkt = K / BK;
  stage(0, 0); stage(1, 1); stage(2, 2);
  for (int t = 0; t < nkt; t += 4) {
    #pragma unroll
    for (int r = 0; r < 4; ++r) {
      int t3 = t + r + 3; if (t3 >= nkt) t3 -= nkt;
      gate_bar<2 * LPS>();
      stage((r + 3) & 3, t3);
      compute(r);
    }
  }
  asm volatile("s_waitcnt vmcnt(0)" ::: "memory");

  #pragma unroll
  for (int m = 0; m < MF; ++m) {
    #pragma unroll
    for (int j = 0; j < 4; ++j) {
      const size_t orow = (size_t)mt * BM + MO + m * 16 + g * 4 + j;
      #pragma unroll
      for (int n = 0; n < NF; ++n) {
        const int gcol = nt * BN + NO + n * 16 + c;
        const float v = acc[m][n][j];
        if constexpr (MODE == 2) ((float*)Cout)[orow * ldc + gcol] = v;
        else ((unsigned short*)Cout)[orow * ldc + gcol] = f2bf(v);
      }
    }
  }
}

// ---------------- flash attention per (bt, head): 4 waves x 16 queries ----------------
__global__ __launch_bounds__(256) void k_attn(
    const unsigned short* __restrict__ q,   // [BT*64][512] bf16 (scale 1/8 pre-folded)
    const unsigned short* __restrict__ kv,  // [BT*1024][1024] bf16: k | v
    unsigned short* __restrict__ ao)        // [BT*64][512] bf16
{
  __shared__ __attribute__((aligned(16))) unsigned short Vt[64 * 64];  // [d][key] swizzled
  const int bid = blockIdx.x;
  const int bt = bid >> 3, h = bid & 7;
  const int tid = threadIdx.x;
  const int wid = tid >> 6, lane = tid & 63;
  const int g = lane >> 4, c = lane & 15;

  const size_t qoff = ((size_t)bt * 64 + wid * 16 + c) * 512 + h * 64;
  const bfrag8 qf0 = *(const bfrag8*)(q + qoff + g * 8);
  const bfrag8 qf1 = *(const bfrag8*)(q + qoff + 32 + g * 8);

  const f32x4 zz = {0.f, 0.f, 0.f, 0.f};
  f32x4 o[4] = {zz, zz, zz, zz};
  float m_run = -1e30f, l_run = 0.f;

  const size_t kvbase = (size_t)bt * 1024 * 1024;
  const unsigned short* kbase = kv + kvbase + h * 64;
  const unsigned short* vbase = kv + kvbase + 512 + h * 64;

  for (int ch = 0; ch < 16; ++ch) {            // 16 chunks of 64 keys
    #pragma unroll
    for (int rr = 0; rr < 2; ++rr) {           // stage V transposed + XOR-swizzled
      const int key = rr * 32 + (tid >> 3);
      const int d0 = (tid & 7) * 8;
      const bfrag8 vv = *(const bfrag8*)(vbase + (size_t)(ch * 64 + key) * 1024 + d0);
      #pragma unroll
      for (int j = 0; j < 8; ++j)
        Vt[(d0 + j) * 64 + (key ^ (j << 3))] = (unsigned short)vv[j];
    }
    __syncthreads();
    #pragma unroll
    for (int ks = 0; ks < 2; ++ks) {           // 2 x 32-key steps
      const int kb = ch * 64 + ks * 32;
      f32x4 s[2];
      #pragma unroll
      for (int t = 0; t < 2; ++t) {            // key permutation: row m -> key 8*(m>>2)+4t+(m&3)
        const int kr = ((c >> 2) << 3) + (t << 2) + (c & 3);
        const unsigned short* krow = kbase + (size_t)(kb + kr) * 1024;
        s[t] = zz;
        s[t] = __builtin_amdgcn_mfma_f32_16x16x32_bf16(*(const bfrag8*)(krow + g * 8),      qf0, s[t], 0, 0, 0);
        s[t] = __builtin_amdgcn_mfma_f32_16x16x32_bf16(*(const bfrag8*)(krow + 32 + g * 8), qf1, s[t], 0, 0, 0);
      }
      float pm = s[0][0];
      #pragma unroll
      for (int i = 1; i < 4; ++i) pm = fmaxf(pm, s[0][i]);
      #pragma unroll
      for (int i = 0; i < 4; ++i) pm = fmaxf(pm, s[1][i]);
      pm = fmaxf(pm, __shfl_xor(pm, 16));
      pm = fmaxf(pm, __shfl_xor(pm, 32));
      const float mn = fmaxf(m_run, pm);
      const float alpha = __expf(m_run - mn);
      float p[8];
      #pragma unroll
      for (int i = 0; i < 4; ++i) p[i]     = __expf(s[0][i] - mn);
      #pragma unroll
      for (int i = 0; i < 4; ++i) p[4 + i] = __expf(s[1][i] - mn);
      float ts = 0.f;
      #pragma unroll
      for (int i = 0; i < 8; ++i) ts += p[i];
      ts += __shfl_xor(ts, 16);
      ts += __shfl_xor(ts, 32);
      l_run = l_run * alpha + ts;
      m_run = mn;
      float ar[4];
      #pragma unroll
      for (int rj = 0; rj < 4; ++rj) ar[rj] = __shfl(alpha, g * 4 + rj);
      #pragma unroll
      for (int db = 0; db < 4; ++db)
        #pragma unroll
        for (int j = 0; j < 4; ++j) o[db][j] *= ar[j];
      bfrag8 pa;
      #pragma unroll
      for (int i = 0; i < 8; ++i) pa[i] = (short)f2bf(p[i]);
      #pragma unroll
      for (int db = 0; db < 4; ++db) {
        const int d = db * 16 + c;
        const bfrag8 vb = *(const bfrag8*)(Vt + d * 64 + ((ks * 32 + g * 8) ^ ((c & 7) << 3)));
        o[db] = __builtin_amdgcn_mfma_f32_16x16x32_bf16(pa, vb, o[db], 0, 0, 0);
      }
    }
    __syncthreads();
  }
  float lr[4];
  #pragma unroll
  for (int rj = 0; rj < 4; ++rj) lr[rj] = __shfl(l_run, g * 4 + rj);
  #pragma unroll
  for (int db = 0; db < 4; ++db)
    #pragma unroll
    for (int j = 0; j < 4; ++j) {
      const float val = o[db][j] / lr[j];
      ao[((size_t)bt * 64 + wid * 16 + g * 4 + j) * 512 + h * 64 + db * 16 + c] = f2bf(val);
    }
}

// --------------------------------- launch -------------------------------------------
extern "C" void kernel_launch(void* const* d_in, const int* in_sizes, int n_in,
                              void* d_out, int out_size, void* d_ws, size_t ws_size,
                              hipStream_t stream)
{
  const float* x    = (const float*)d_in[0];
  const float* lat  = (const float*)d_in[1];
  const float* nm_w = (const float*)d_in[2];
  const float* nm_b = (const float*)d_in[3];
  const float* nl_w = (const float*)d_in[4];
  const float* nl_b = (const float*)d_in[5];
  const float* Wq   = (const float*)d_in[6];
  const float* Wkv  = (const float*)d_in[7];
  const float* Wout = (const float*)d_in[8];

  char* p = (char*)d_ws;
  auto take = [&](size_t bytes) { char* r = p; p += (bytes + 255) & ~(size_t)255; return r; };
  unsigned short* kvb   = (unsigned short*)take(64ull * 1024 * 1024 * 2);  // kv bf16
  unsigned short* lnb   = (unsigned short*)take(4096ull * 2048 * 2);       // LN(latents)
  unsigned short* qbuf  = (unsigned short*)take(4096ull * 512 * 2);        // q (scaled)
  unsigned short* aob   = (unsigned short*)take(4096ull * 512 * 2);        // attn out
  unsigned short* WqT   = (unsigned short*)take(512ull * 2048 * 2);
  unsigned short* WkvT  = (unsigned short*)take(1024ull * 1024 * 2);
  unsigned short* WoutT = (unsigned short*)take(2048ull * 512 * 2);
  float* c1   = (float*)take(1024 * 4);
  float* c2   = (float*)take(1024 * 4);
  float* part = (float*)take(32ull * 1024 * 4);
  if ((size_t)(p - (char*)d_ws) > ws_size) return;  // insufficient workspace: fail loudly

  k_transpose_cast<<<dim3(64 * 16), 256, 0, stream>>>(Wq,   WqT,   2048,  512, nullptr, 0.125f);
  k_transpose_cast<<<dim3(32 * 32), 256, 0, stream>>>(Wkv,  WkvT,  1024, 1024, nm_w,    1.0f);
  k_transpose_cast<<<dim3(16 * 64), 256, 0, stream>>>(Wout, WoutT,  512, 2048, nullptr, 1.0f);
  k_c1c2_part<<<dim3(16, 4), 256, 0, stream>>>(Wkv, nm_w, nm_b, part);
  k_c1c2_red<<<dim3(4), 256, 0, stream>>>(part, c1, c2);
  k_lnlat<<<dim3(4096), 256, 0, stream>>>(lat, nl_w, nl_b, lnb);

  // kv = LN(x) @ Wkv, stats fused in-GEMM: [65536 x 1024 x 1024], 8-phase 256^2
  k_gemm8f<<<dim3(1024), 512, 0, stream>>>(x, WkvT, kvb, c1, c2);
  // q = LN(latents) @ (Wq/8): [4096 x 512 x 2048], 64x128 tiles -> 256 blocks
  k_gemm<64, 128, 1, 4, 256, 1><<<dim3(256), 256, 0, stream>>>(
      lnb, 2048, WqT, 2048, 2048, 64, 4, qbuf, 512);

  k_attn<<<dim3(512), 256, 0, stream>>>(qbuf, kvb, aob);

  // out = attnout @ Wout: [4096 x 2048 x 512] -> f32, 64x128 tiles -> 1024 blocks
  k_gemm<64, 128, 1, 4, 256, 2><<<dim3(1024), 256, 0, stream>>>(
      aob, 512, WoutT, 512, 512, 64, 16, d_out, 2048);
}

// Round 10
// 363.042 us; speedup vs baseline: 2.4710x; 2.4710x over previous
//
#include <hip/hip_runtime.h>

typedef __attribute__((ext_vector_type(8))) short bfrag8;   // 8 x bf16 (4 VGPRs)
typedef __attribute__((ext_vector_type(4))) float f32x4;    // MFMA accumulator

typedef const unsigned int __attribute__((address_space(1)))* gas1_u32;
typedef unsigned int __attribute__((address_space(3)))* gas3_u32;

#define DEV __device__ __forceinline__

DEV unsigned short f2bf(float f) {              // f32 -> bf16 bits, RNE
  unsigned int u = __builtin_bit_cast(unsigned int, f);
  u += 0x7fffu + ((u >> 16) & 1u);
  return (unsigned short)(u >> 16);
}

DEV void gload_lds16(const void* g, void* l) {  // async global->LDS, 16B/lane
  __builtin_amdgcn_global_load_lds((gas1_u32)g, (gas3_u32)l, 16, 0, 0);
}

// =====================================================================================
// k_pre: all independent preprocessing in ONE launch (block-range dispatch).
//  [0,16384)      x row stats + bf16 cast (4 rows/block, 1 wave/row)
//  [16384,20480)  LN(latents) -> bf16 (1 row/block)
//  [20480,23552)  weight transposes+cast (Wq*0.125, Wkv*nm_w, Wout)
//  [23552,23616)  c1c2 partials (16 k-chunks x 4 n-blocks)
// All branches read only inputs and write disjoint ws regions.
// =====================================================================================
__global__ __launch_bounds__(256) void k_pre(
    const float* __restrict__ x, unsigned short* __restrict__ xb,
    float* __restrict__ mu, float* __restrict__ rstd,
    const float* __restrict__ lat, const float* __restrict__ nl_w,
    const float* __restrict__ nl_b, unsigned short* __restrict__ lnb,
    const float* __restrict__ Wq,   unsigned short* __restrict__ WqT,
    const float* __restrict__ Wkv,  unsigned short* __restrict__ WkvT,
    const float* __restrict__ Wout, unsigned short* __restrict__ WoutT,
    const float* __restrict__ nm_w, const float* __restrict__ nm_b,
    float* __restrict__ part)
{
  __shared__ float smem[32 * 33];
  const int bid = blockIdx.x, tid = threadIdx.x;
  const int wid = tid >> 6, lane = tid & 63;

  if (bid < 16384) {                           // ---- x stats + cast ----
    const int row = bid * 4 + wid;
    const float* base = x + (size_t)row * 1024;
    float4 v[4];
    #pragma unroll
    for (int i = 0; i < 4; ++i) v[i] = ((const float4*)base)[i * 64 + lane];
    float s = 0.f, q = 0.f;
    #pragma unroll
    for (int i = 0; i < 4; ++i) {
      s += v[i].x + v[i].y + v[i].z + v[i].w;
      q += v[i].x*v[i].x + v[i].y*v[i].y + v[i].z*v[i].z + v[i].w*v[i].w;
    }
    #pragma unroll
    for (int off = 32; off >= 1; off >>= 1) { s += __shfl_xor(s, off); q += __shfl_xor(q, off); }
    const float m  = s * (1.0f/1024.0f);
    const float var = q * (1.0f/1024.0f) - m * m;
    const float rs = rsqrtf(var + 1e-5f);
    if (lane == 0) { mu[row] = m; rstd[row] = rs; }
    unsigned short* ob = xb + (size_t)row * 1024;
    #pragma unroll
    for (int i = 0; i < 4; ++i) {
      ushort4 o;
      o.x = f2bf(v[i].x); o.y = f2bf(v[i].y); o.z = f2bf(v[i].z); o.w = f2bf(v[i].w);
      ((ushort4*)ob)[i * 64 + lane] = o;
    }
    return;
  }
  if (bid < 20480) {                           // ---- LN(latents) ----
    const int row = bid - 16384;
    const float* base = lat + (size_t)row * 2048;
    const float4 v0 = ((const float4*)base)[tid];
    const float4 v1 = ((const float4*)base)[256 + tid];
    float s = v0.x+v0.y+v0.z+v0.w + v1.x+v1.y+v1.z+v1.w;
    float q = v0.x*v0.x+v0.y*v0.y+v0.z*v0.z+v0.w*v0.w
            + v1.x*v1.x+v1.y*v1.y+v1.z*v1.z+v1.w*v1.w;
    #pragma unroll
    for (int off = 32; off >= 1; off >>= 1) { s += __shfl_xor(s, off); q += __shfl_xor(q, off); }
    if (lane == 0) { smem[wid] = s; smem[4 + wid] = q; }
    __syncthreads();
    s = smem[0] + smem[1] + smem[2] + smem[3];
    q = smem[4] + smem[5] + smem[6] + smem[7];
    const float m  = s * (1.0f/2048.0f);
    const float var = q * (1.0f/2048.0f) - m * m;
    const float rs = rsqrtf(var + 1e-5f);
    const float4 w0 = ((const float4*)nl_w)[tid], w1 = ((const float4*)nl_w)[256 + tid];
    const float4 b0 = ((const float4*)nl_b)[tid], b1 = ((const float4*)nl_b)[256 + tid];
    ushort4 o0, o1;
    o0.x = f2bf((v0.x - m) * rs * w0.x + b0.x);
    o0.y = f2bf((v0.y - m) * rs * w0.y + b0.y);
    o0.z = f2bf((v0.z - m) * rs * w0.z + b0.z);
    o0.w = f2bf((v0.w - m) * rs * w0.w + b0.w);
    o1.x = f2bf((v1.x - m) * rs * w1.x + b1.x);
    o1.y = f2bf((v1.y - m) * rs * w1.y + b1.y);
    o1.z = f2bf((v1.z - m) * rs * w1.z + b1.z);
    o1.w = f2bf((v1.w - m) * rs * w1.w + b1.w);
    ((ushort4*)(lnb + (size_t)row * 2048))[tid] = o0;
    ((ushort4*)(lnb + (size_t)row * 2048))[256 + tid] = o1;
    return;
  }
  if (bid < 23552) {                           // ---- weight transposes ----
    int tb = bid - 20480;
    const float* src; unsigned short* dst; int Kd, N; const float* rsc; float sc;
    if (tb < 1024)      { src = Wq;   dst = WqT;   Kd = 2048; N = 512;  rsc = nullptr; sc = 0.125f; }
    else if (tb < 2048) { tb -= 1024; src = Wkv;  dst = WkvT;  Kd = 1024; N = 1024; rsc = nm_w;   sc = 1.0f; }
    else                { tb -= 2048; src = Wout; dst = WoutT; Kd = 512;  N = 2048; rsc = nullptr; sc = 1.0f; }
    float (*tile)[33] = (float(*)[33])smem;
    const int tx = tid & 31, ty = tid >> 5;
    const int ntiles = N >> 5;
    const int k0 = (tb / ntiles) << 5;
    const int n0 = (tb % ntiles) << 5;
    #pragma unroll
    for (int r = 0; r < 4; ++r) {
      const int kk = ty + r * 8;
      float v = src[(size_t)(k0 + kk) * N + n0 + tx] * sc;
      if (rsc) v *= rsc[k0 + kk];
      tile[kk][tx] = v;
    }
    __syncthreads();
    #pragma unroll
    for (int r = 0; r < 4; ++r) {
      const int nn = ty + r * 8;
      dst[(size_t)(n0 + nn) * Kd + k0 + tx] = f2bf(tile[tx][nn]);
    }
    return;
  }
  {                                            // ---- c1c2 partials ----
    const int cb = bid - 23552;
    const int kc = cb >> 2;
    const int n  = (cb & 3) * 256 + tid;
    float s1 = 0.f, s2 = 0.f;
    const int k0 = kc * 64;
    for (int k = k0; k < k0 + 64; ++k) {
      const float wv = Wkv[(size_t)k * 1024 + n];
      s1 += nm_w[k] * wv;
      s2 += nm_b[k] * wv;
    }
    part[(size_t)(kc * 2 + 0) * 1024 + n] = s1;
    part[(size_t)(kc * 2 + 1) * 1024 + n] = s2;
  }
}

__global__ __launch_bounds__(256) void k_c1c2_red(
    const float* __restrict__ part, float* __restrict__ c1, float* __restrict__ c2)
{
  const int n = blockIdx.x * 256 + threadIdx.x;
  float s1 = 0.f, s2 = 0.f;
  #pragma unroll
  for (int kc = 0; kc < 16; ++kc) {
    s1 += part[(size_t)(kc * 2 + 0) * 1024 + n];
    s2 += part[(size_t)(kc * 2 + 1) * 1024 + n];
  }
  c1[n] = s1; c2[n] = s2;
}

// =====================================================================================
// kv GEMM, 8-phase (R6 structure verbatim; 906 TF measured). Tile 256x256, BK=64,
// 8 waves. Phase = {ds_reads, 1 half-tile stage, setprio, MFMA, setprio(0), GATE/BAR}.
// vmcnt(4) counted gates; slot-rotated conflict-free LDS; LN folded in epilogue.
// =====================================================================================
#define BAR8   __builtin_amdgcn_s_barrier()
#define GATE4  asm volatile("s_waitcnt vmcnt(4)\n\ts_barrier" ::: "memory")

__global__ __launch_bounds__(512, 2) void k_gemm8(
    const unsigned short* __restrict__ A,
    const unsigned short* __restrict__ Bt,
    unsigned short* __restrict__ C,
    const float* __restrict__ mu, const float* __restrict__ rstd,
    const float* __restrict__ c1, const float* __restrict__ c2)
{
  constexpr int NKT = 16;                     // K=1024 / BK=64
  __shared__ __attribute__((aligned(16))) char lds[131072];

  int bid = blockIdx.x;
  { const int nwg = gridDim.x; const int q = nwg >> 3; bid = (bid & 7) * q + (bid >> 3); }
  const int mt = bid >> 2, nt = bid & 3;      // nt fastest: 4 blocks share A panel
  const int tid = threadIdx.x;
  const int wid = tid >> 6, lane = tid & 63;
  const int g = lane >> 4, c = lane & 15;
  const int wr = wid >> 2, wc = wid & 3;
  const int MO = wr * 128, NO = wc * 64;

  const unsigned short* gA = A + (size_t)mt * 256 * 1024;
  const unsigned short* gB = Bt + (size_t)nt * 256 * 1024;

  const f32x4 zz = {0.f, 0.f, 0.f, 0.f};
  f32x4 acc[8][4];
  #pragma unroll
  for (int m = 0; m < 8; ++m)
    #pragma unroll
    for (int n = 0; n < 4; ++n) acc[m][n] = zz;

  auto stageA = [&](int buf, int kk, int kt) {
    #pragma unroll
    for (int i = 0; i < 2; ++i) {
      const int o = (i * 512 + tid) * 16;
      const int row = o >> 6;
      const int ss = ((((o >> 4) & 3) - (row >> 1)) & 3);
      gload_lds16((const char*)(gA + (size_t)row * 1024 + kt * 64 + kk * 32) + ss * 16,
                  lds + buf * 32768 + kk * 16384 + o);
    }
  };
  auto stageB = [&](int buf, int kk, int kt) {
    #pragma unroll
    for (int i = 0; i < 2; ++i) {
      const int o = (i * 512 + tid) * 16;
      const int row = o >> 6;
      const int ss = ((((o >> 4) & 3) - (row >> 1)) & 3);
      gload_lds16((const char*)(gB + (size_t)row * 1024 + kt * 64 + kk * 32) + ss * 16,
                  lds + 65536 + buf * 32768 + kk * 16384 + o);
    }
  };
  auto rdA = [&](int buf, int kk, int m) -> bfrag8 {
    const int row = MO + m * 16 + c;
    return *(const bfrag8*)(lds + buf * 32768 + kk * 16384 + row * 64
                            + (((g + (row >> 1)) & 3) << 4));
  };
  auto rdB = [&](int buf, int kk, int n) -> bfrag8 {
    const int row = NO + n * 16 + c;
    return *(const bfrag8*)(lds + 65536 + buf * 32768 + kk * 16384 + row * 64
                            + (((g + (row >> 1)) & 3) << 4));
  };

  bfrag8 a[8], b0[4], b1[4];

  auto tile4 = [&](int buf, int sb, int ukt) {
    #pragma unroll
    for (int m = 0; m < 8; ++m) a[m] = rdA(buf, 0, m);
    #pragma unroll
    for (int n = 0; n < 4; ++n) b0[n] = rdB(buf, 0, n);
    stageA(sb, 0, ukt);
    __builtin_amdgcn_s_setprio(1);
    #pragma unroll
    for (int m = 0; m < 8; ++m) {
      acc[m][0] = __builtin_amdgcn_mfma_f32_16x16x32_bf16(a[m], b0[0], acc[m][0], 0, 0, 0);
      acc[m][1] = __builtin_amdgcn_mfma_f32_16x16x32_bf16(a[m], b0[1], acc[m][1], 0, 0, 0);
    }
    __builtin_amdgcn_s_setprio(0);
    GATE4;
    #pragma unroll
    for (int n = 0; n < 4; ++n) b1[n] = rdB(buf, 1, n);
    stageB(sb, 0, ukt);
    __builtin_amdgcn_s_setprio(1);
    #pragma unroll
    for (int m = 0; m < 8; ++m) {
      acc[m][2] = __builtin_amdgcn_mfma_f32_16x16x32_bf16(a[m], b0[2], acc[m][2], 0, 0, 0);
      acc[m][3] = __builtin_amdgcn_mfma_f32_16x16x32_bf16(a[m], b0[3], acc[m][3], 0, 0, 0);
    }
    __builtin_amdgcn_s_setprio(0);
    GATE4;
    #pragma unroll
    for (int m = 0; m < 8; ++m) a[m] = rdA(buf, 1, m);
    stageB(sb, 1, ukt);
    __builtin_amdgcn_s_setprio(1);
    #pragma unroll
    for (int m = 0; m < 8; ++m) {
      acc[m][0] = __builtin_amdgcn_mfma_f32_16x16x32_bf16(a[m], b1[0], acc[m][0], 0, 0, 0);
      acc[m][1] = __builtin_amdgcn_mfma_f32_16x16x32_bf16(a[m], b1[1], acc[m][1], 0, 0, 0);
    }
    __builtin_amdgcn_s_setprio(0);
    BAR8;
    stageA(sb, 1, ukt);
    __builtin_amdgcn_s_setprio(1);
    #pragma unroll
    for (int m = 0; m < 8; ++m) {
      acc[m][2] = __builtin_amdgcn_mfma_f32_16x16x32_bf16(a[m], b1[2], acc[m][2], 0, 0, 0);
      acc[m][3] = __builtin_amdgcn_mfma_f32_16x16x32_bf16(a[m], b1[3], acc[m][3], 0, 0, 0);
    }
    __builtin_amdgcn_s_setprio(0);
    GATE4;
  };

  stageA(0, 0, 0); stageB(0, 0, 0); stageB(0, 1, 0); stageA(0, 1, 0);
  GATE4;

  for (int t = 0; t < NKT; t += 2) {
    const int u2 = (t + 2 < NKT) ? t + 2 : 0;   // wrap dummy keeps vmcnt uniform
    tile4(0, 1, t + 1);
    tile4(1, 0, u2);
  }
  asm volatile("s_waitcnt vmcnt(0)" ::: "memory");

  // epilogue: kv = rstd*(acc - mu*c1) + c2 -> bf16
  #pragma unroll
  for (int m = 0; m < 8; ++m) {
    #pragma unroll
    for (int j = 0; j < 4; ++j) {
      const size_t orow = (size_t)mt * 256 + MO + m * 16 + g * 4 + j;
      const float rs = rstd[orow], muv = mu[orow];
      #pragma unroll
      for (int n = 0; n < 4; ++n) {
        const int gcol = nt * 256 + NO + n * 16 + c;
        const float v = rs * (acc[m][n][j] - muv * c1[gcol]) + c2[gcol];
        C[orow * 1024 + gcol] = f2bf(v);
      }
    }
  }
}

// =====================================================================================
// small GEMM (q / out): R2 two-buffer stage-ahead structure (measured-better for these
// latency-bound shapes than counted-gate 4-region), BK=64, mod-8 rotation swizzle
// (conflict-free b128; logical slot l at physical (l+row)&7, source pre-rotated).
// MODE 1: plain -> bf16        MODE 2: plain -> f32
// =====================================================================================
template<int BM, int BN, int WM, int WN, int NT, int MODE>
__global__ __launch_bounds__(NT, 2) void k_gemm(
    const unsigned short* __restrict__ A, int lda,
    const unsigned short* __restrict__ Bt, int ldb,
    int K, int mtiles, int ntiles,
    void* __restrict__ Cout, int ldc)
{
  constexpr int BK = 64;
  constexpr int NW = NT / 64;
  constexpr int MF = (BM / WM) / 16;
  constexpr int NF = (BN / WN) / 16;
  constexpr int LA = (BM * BK) / (8 * NT);
  constexpr int LB = (BN * BK) / (8 * NT);
  static_assert(WM * WN == NW, "wave grid");
  static_assert(LA >= 1 && LB >= 1, "tile too small for NT");

  __shared__ __attribute__((aligned(16))) unsigned short As[2][BM * BK];
  __shared__ __attribute__((aligned(16))) unsigned short Bs[2][BN * BK];

  int bid = blockIdx.x;
  {
    const int nwg = gridDim.x;
    if ((nwg & 7) == 0) {
      const int q = nwg >> 3;
      bid = (bid & 7) * q + (bid >> 3);
    }
  }
  const int mt = bid / ntiles, nt = bid % ntiles;
  const int tid = threadIdx.x;
  const int wid = tid >> 6, lane = tid & 63;
  const int g = lane >> 4, c = lane & 15;
  const int wr = wid / WN, wc = wid % WN;
  const int MO = wr * (BM / WM), NO = wc * (BN / WN);

  const unsigned short* gA = A + (size_t)mt * BM * lda;
  const unsigned short* gB = Bt + (size_t)nt * BN * ldb;

  const f32x4 zz = {0.f, 0.f, 0.f, 0.f};
  f32x4 acc[MF][NF];
  #pragma unroll
  for (int m = 0; m < MF; ++m)
    #pragma unroll
    for (int n = 0; n < NF; ++n) acc[m][n] = zz;

  auto stage = [&](int buf, int kt) {
    #pragma unroll
    for (int i = 0; i < LA; ++i) {
      const int o = (i * NT + tid) * 16;
      const int row = o >> 7;                       // 128B rows
      const int sg = (((o >> 4) & 7) - row) & 7;    // pre-rotated source slot
      gload_lds16((const char*)(gA + (size_t)row * lda + kt * BK) + sg * 16,
                  (char*)&As[buf][0] + o);
    }
    #pragma unroll
    for (int i = 0; i < LB; ++i) {
      const int o = (i * NT + tid) * 16;
      const int row = o >> 7;
      const int sg = (((o >> 4) & 7) - row) & 7;
      gload_lds16((const char*)(gB + (size_t)row * ldb + kt * BK) + sg * 16,
                  (char*)&Bs[buf][0] + o);
    }
  };

  auto compute = [&](int buf) {
    #pragma unroll
    for (int kk = 0; kk < 2; ++kk) {
      bfrag8 af[MF], bf[NF];
      #pragma unroll
      for (int m = 0; m < MF; ++m) {
        const int rw = MO + m * 16 + c;
        af[m] = *(const bfrag8*)((const char*)&As[buf][0] + rw * 128
                                 + (((kk * 4 + g + rw) & 7) << 4));
      }
      #pragma unroll
      for (int n = 0; n < NF; ++n) {
        const int rw = NO + n * 16 + c;
        bf[n] = *(const bfrag8*)((const char*)&Bs[buf][0] + rw * 128
                                 + (((kk * 4 + g + rw) & 7) << 4));
      }
      #pragma unroll
      for (int m = 0; m < MF; ++m)
        #pragma unroll
        for (int n = 0; n < NF; ++n)
          acc[m][n] = __builtin_amdgcn_mfma_f32_16x16x32_bf16(af[m], bf[n], acc[m][n], 0, 0, 0);
    }
  };

  const int nkt = K / BK;                    // 32 (q) / 8 (out), even
  stage(0, 0);
  __syncthreads();
  for (int t = 0; t < nkt; t += 2) {
    if (t + 1 < nkt) stage(1, t + 1);
    compute(0);
    __syncthreads();                          // drains vmcnt: buf1 landed
    if (t + 2 < nkt) stage(0, t + 2);
    if (t + 1 < nkt) compute(1);
    __syncthreads();
  }

  #pragma unroll
  for (int m = 0; m < MF; ++m) {
    #pragma unroll
    for (int j = 0; j < 4; ++j) {
      const size_t orow = (size_t)mt * BM + MO + m * 16 + g * 4 + j;
      #pragma unroll
      for (int n = 0; n < NF; ++n) {
        const int gcol = nt * BN + NO + n * 16 + c;
        const float v = acc[m][n][j];
        if constexpr (MODE == 2) ((float*)Cout)[orow * ldc + gcol] = v;
        else ((unsigned short*)Cout)[orow * ldc + gcol] = f2bf(v);
      }
    }
  }
}

// ---------------- flash attention per (bt, head): 4 waves x 16 queries ----------------
__global__ __launch_bounds__(256) void k_attn(
    const unsigned short* __restrict__ q,   // [BT*64][512] bf16 (scale 1/8 pre-folded)
    const unsigned short* __restrict__ kv,  // [BT*1024][1024] bf16: k | v
    unsigned short* __restrict__ ao)        // [BT*64][512] bf16
{
  __shared__ __attribute__((aligned(16))) unsigned short Vt[64 * 64];  // [d][key] swizzled
  const int bid = blockIdx.x;
  const int bt = bid >> 3, h = bid & 7;
  const int tid = threadIdx.x;
  const int wid = tid >> 6, lane = tid & 63;
  const int g = lane >> 4, c = lane & 15;

  const size_t qoff = ((size_t)bt * 64 + wid * 16 + c) * 512 + h * 64;
  const bfrag8 qf0 = *(const bfrag8*)(q + qoff + g * 8);
  const bfrag8 qf1 = *(const bfrag8*)(q + qoff + 32 + g * 8);

  const f32x4 zz = {0.f, 0.f, 0.f, 0.f};
  f32x4 o[4] = {zz, zz, zz, zz};
  float m_run = -1e30f, l_run = 0.f;

  const size_t kvbase = (size_t)bt * 1024 * 1024;
  const unsigned short* kbase = kv + kvbase + h * 64;
  const unsigned short* vbase = kv + kvbase + 512 + h * 64;

  for (int ch = 0; ch < 16; ++ch) {            // 16 chunks of 64 keys
    #pragma unroll
    for (int rr = 0; rr < 2; ++rr) {           // stage V transposed + XOR-swizzled
      const int key = rr * 32 + (tid >> 3);
      const int d0 = (tid & 7) * 8;
      const bfrag8 vv = *(const bfrag8*)(vbase + (size_t)(ch * 64 + key) * 1024 + d0);
      #pragma unroll
      for (int j = 0; j < 8; ++j)
        Vt[(d0 + j) * 64 + (key ^ (j << 3))] = (unsigned short)vv[j];
    }
    __syncthreads();
    #pragma unroll
    for (int ks = 0; ks < 2; ++ks) {           // 2 x 32-key steps
      const int kb = ch * 64 + ks * 32;
      f32x4 s[2];
      #pragma unroll
      for (int t = 0; t < 2; ++t) {            // key permutation: row m -> key 8*(m>>2)+4t+(m&3)
        const int kr = ((c >> 2) << 3) + (t << 2) + (c & 3);
        const unsigned short* krow = kbase + (size_t)(kb + kr) * 1024;
        s[t] = zz;
        s[t] = __builtin_amdgcn_mfma_f32_16x16x32_bf16(*(const bfrag8*)(krow + g * 8),      qf0, s[t], 0, 0, 0);
        s[t] = __builtin_amdgcn_mfma_f32_16x16x32_bf16(*(const bfrag8*)(krow + 32 + g * 8), qf1, s[t], 0, 0, 0);
      }
      float pm = s[0][0];
      #pragma unroll
      for (int i = 1; i < 4; ++i) pm = fmaxf(pm, s[0][i]);
      #pragma unroll
      for (int i = 0; i < 4; ++i) pm = fmaxf(pm, s[1][i]);
      pm = fmaxf(pm, __shfl_xor(pm, 16));
      pm = fmaxf(pm, __shfl_xor(pm, 32));
      const float mn = fmaxf(m_run, pm);
      const float alpha = __expf(m_run - mn);
      float p[8];
      #pragma unroll
      for (int i = 0; i < 4; ++i) p[i]     = __expf(s[0][i] - mn);
      #pragma unroll
      for (int i = 0; i < 4; ++i) p[4 + i] = __expf(s[1][i] - mn);
      float ts = 0.f;
      #pragma unroll
      for (int i = 0; i < 8; ++i) ts += p[i];
      ts += __shfl_xor(ts, 16);
      ts += __shfl_xor(ts, 32);
      l_run = l_run * alpha + ts;
      m_run = mn;
      float ar[4];
      #pragma unroll
      for (int rj = 0; rj < 4; ++rj) ar[rj] = __shfl(alpha, g * 4 + rj);
      #pragma unroll
      for (int db = 0; db < 4; ++db)
        #pragma unroll
        for (int j = 0; j < 4; ++j) o[db][j] *= ar[j];
      bfrag8 pa;
      #pragma unroll
      for (int i = 0; i < 8; ++i) pa[i] = (short)f2bf(p[i]);
      #pragma unroll
      for (int db = 0; db < 4; ++db) {
        const int d = db * 16 + c;
        const bfrag8 vb = *(const bfrag8*)(Vt + d * 64 + ((ks * 32 + g * 8) ^ ((c & 7) << 3)));
        o[db] = __builtin_amdgcn_mfma_f32_16x16x32_bf16(pa, vb, o[db], 0, 0, 0);
      }
    }
    __syncthreads();
  }
  float lr[4];
  #pragma unroll
  for (int rj = 0; rj < 4; ++rj) lr[rj] = __shfl(l_run, g * 4 + rj);
  #pragma unroll
  for (int db = 0; db < 4; ++db)
    #pragma unroll
    for (int j = 0; j < 4; ++j) {
      const float val = o[db][j] / lr[j];
      ao[((size_t)bt * 64 + wid * 16 + g * 4 + j) * 512 + h * 64 + db * 16 + c] = f2bf(val);
    }
}

// --------------------------------- launch -------------------------------------------
extern "C" void kernel_launch(void* const* d_in, const int* in_sizes, int n_in,
                              void* d_out, int out_size, void* d_ws, size_t ws_size,
                              hipStream_t stream)
{
  const float* x    = (const float*)d_in[0];
  const float* lat  = (const float*)d_in[1];
  const float* nm_w = (const float*)d_in[2];
  const float* nm_b = (const float*)d_in[3];
  const float* nl_w = (const float*)d_in[4];
  const float* nl_b = (const float*)d_in[5];
  const float* Wq   = (const float*)d_in[6];
  const float* Wkv  = (const float*)d_in[7];
  const float* Wout = (const float*)d_in[8];

  char* p = (char*)d_ws;
  auto take = [&](size_t bytes) { char* r = p; p += (bytes + 255) & ~(size_t)255; return r; };
  unsigned short* xb    = (unsigned short*)take(64ull * 1024 * 1024 * 2);  // bf16(x)
  unsigned short* kvb   = (unsigned short*)take(64ull * 1024 * 1024 * 2);  // kv bf16
  unsigned short* lnb   = (unsigned short*)take(4096ull * 2048 * 2);       // LN(latents)
  unsigned short* qbuf  = (unsigned short*)take(4096ull * 512 * 2);        // q (scaled)
  unsigned short* aob   = (unsigned short*)take(4096ull * 512 * 2);        // attn out
  unsigned short* WqT   = (unsigned short*)take(512ull * 2048 * 2);
  unsigned short* WkvT  = (unsigned short*)take(1024ull * 1024 * 2);
  unsigned short* WoutT = (unsigned short*)take(2048ull * 512 * 2);
  float* muv  = (float*)take(65536ull * 4);
  float* rsd  = (float*)take(65536ull * 4);
  float* c1   = (float*)take(1024 * 4);
  float* c2   = (float*)take(1024 * 4);
  float* part = (float*)take(32ull * 1024 * 4);
  if ((size_t)(p - (char*)d_ws) > ws_size) return;  // insufficient workspace: fail loudly

  // all independent preprocessing in one launch
  k_pre<<<dim3(23616), 256, 0, stream>>>(x, xb, muv, rsd,
                                         lat, nl_w, nl_b, lnb,
                                         Wq, WqT, Wkv, WkvT, Wout, WoutT,
                                         nm_w, nm_b, part);
  k_c1c2_red<<<dim3(4), 256, 0, stream>>>(part, c1, c2);

  // kv = LN(x) @ Wkv (LN in epilogue): [65536 x 1024 x 1024], 8-phase 256^2
  k_gemm8<<<dim3(1024), 512, 0, stream>>>(xb, WkvT, kvb, muv, rsd, c1, c2);
  // q = LN(latents) @ (Wq/8): [4096 x 512 x 2048]
  k_gemm<64, 128, 1, 4, 256, 1><<<dim3(256), 256, 0, stream>>>(
      lnb, 2048, WqT, 2048, 2048, 64, 4, qbuf, 512);

  k_attn<<<dim3(512), 256, 0, stream>>>(qbuf, kvb, aob);

  // out = attnout @ Wout: [4096 x 2048 x 512] -> f32
  k_gemm<64, 128, 1, 4, 256, 2><<<dim3(1024), 256, 0, stream>>>(
      aob, 512, WoutT, 512, 512, 64, 16, d_out, 2048);
}

// Round 11
// 355.980 us; speedup vs baseline: 2.5200x; 1.0198x over previous
//
#include <hip/hip_runtime.h>

typedef __attribute__((ext_vector_type(8))) short bfrag8;   // 8 x bf16 (4 VGPRs)
typedef __attribute__((ext_vector_type(4))) float f32x4;    // MFMA accumulator

typedef const unsigned int __attribute__((address_space(1)))* gas1_u32;
typedef unsigned int __attribute__((address_space(3)))* gas3_u32;

#define DEV __device__ __forceinline__

DEV unsigned short f2bf(float f) {              // f32 -> bf16 bits, RNE
  unsigned int u = __builtin_bit_cast(unsigned int, f);
  u += 0x7fffu + ((u >> 16) & 1u);
  return (unsigned short)(u >> 16);
}

DEV void gload_lds16(const void* g, void* l) {  // async global->LDS, 16B/lane
  __builtin_amdgcn_global_load_lds((gas1_u32)g, (gas3_u32)l, 16, 0, 0);
}

// =====================================================================================
// k_pre: all independent preprocessing in ONE launch (block-range dispatch).
//  [0,16384)      x row stats + bf16 cast (4 rows/block, 1 wave/row)
//  [16384,20480)  LN(latents) -> bf16 (1 row/block)
//  [20480,23552)  weight transposes+cast (Wq*0.125, Wkv*nm_w, Wout)
//  [23552,23616)  c1c2 partials (16 k-chunks x 4 n-blocks)
// =====================================================================================
__global__ __launch_bounds__(256) void k_pre(
    const float* __restrict__ x, unsigned short* __restrict__ xb,
    float* __restrict__ mu, float* __restrict__ rstd,
    const float* __restrict__ lat, const float* __restrict__ nl_w,
    const float* __restrict__ nl_b, unsigned short* __restrict__ lnb,
    const float* __restrict__ Wq,   unsigned short* __restrict__ WqT,
    const float* __restrict__ Wkv,  unsigned short* __restrict__ WkvT,
    const float* __restrict__ Wout, unsigned short* __restrict__ WoutT,
    const float* __restrict__ nm_w, const float* __restrict__ nm_b,
    float* __restrict__ part)
{
  __shared__ float smem[32 * 33];
  const int bid = blockIdx.x, tid = threadIdx.x;
  const int wid = tid >> 6, lane = tid & 63;

  if (bid < 16384) {                           // ---- x stats + cast ----
    const int row = bid * 4 + wid;
    const float* base = x + (size_t)row * 1024;
    float4 v[4];
    #pragma unroll
    for (int i = 0; i < 4; ++i) v[i] = ((const float4*)base)[i * 64 + lane];
    float s = 0.f, q = 0.f;
    #pragma unroll
    for (int i = 0; i < 4; ++i) {
      s += v[i].x + v[i].y + v[i].z + v[i].w;
      q += v[i].x*v[i].x + v[i].y*v[i].y + v[i].z*v[i].z + v[i].w*v[i].w;
    }
    #pragma unroll
    for (int off = 32; off >= 1; off >>= 1) { s += __shfl_xor(s, off); q += __shfl_xor(q, off); }
    const float m  = s * (1.0f/1024.0f);
    const float var = q * (1.0f/1024.0f) - m * m;
    const float rs = rsqrtf(var + 1e-5f);
    if (lane == 0) { mu[row] = m; rstd[row] = rs; }
    unsigned short* ob = xb + (size_t)row * 1024;
    #pragma unroll
    for (int i = 0; i < 4; ++i) {
      ushort4 o;
      o.x = f2bf(v[i].x); o.y = f2bf(v[i].y); o.z = f2bf(v[i].z); o.w = f2bf(v[i].w);
      ((ushort4*)ob)[i * 64 + lane] = o;
    }
    return;
  }
  if (bid < 20480) {                           // ---- LN(latents) ----
    const int row = bid - 16384;
    const float* base = lat + (size_t)row * 2048;
    const float4 v0 = ((const float4*)base)[tid];
    const float4 v1 = ((const float4*)base)[256 + tid];
    float s = v0.x+v0.y+v0.z+v0.w + v1.x+v1.y+v1.z+v1.w;
    float q = v0.x*v0.x+v0.y*v0.y+v0.z*v0.z+v0.w*v0.w
            + v1.x*v1.x+v1.y*v1.y+v1.z*v1.z+v1.w*v1.w;
    #pragma unroll
    for (int off = 32; off >= 1; off >>= 1) { s += __shfl_xor(s, off); q += __shfl_xor(q, off); }
    if (lane == 0) { smem[wid] = s; smem[4 + wid] = q; }
    __syncthreads();
    s = smem[0] + smem[1] + smem[2] + smem[3];
    q = smem[4] + smem[5] + smem[6] + smem[7];
    const float m  = s * (1.0f/2048.0f);
    const float var = q * (1.0f/2048.0f) - m * m;
    const float rs = rsqrtf(var + 1e-5f);
    const float4 w0 = ((const float4*)nl_w)[tid], w1 = ((const float4*)nl_w)[256 + tid];
    const float4 b0 = ((const float4*)nl_b)[tid], b1 = ((const float4*)nl_b)[256 + tid];
    ushort4 o0, o1;
    o0.x = f2bf((v0.x - m) * rs * w0.x + b0.x);
    o0.y = f2bf((v0.y - m) * rs * w0.y + b0.y);
    o0.z = f2bf((v0.z - m) * rs * w0.z + b0.z);
    o0.w = f2bf((v0.w - m) * rs * w0.w + b0.w);
    o1.x = f2bf((v1.x - m) * rs * w1.x + b1.x);
    o1.y = f2bf((v1.y - m) * rs * w1.y + b1.y);
    o1.z = f2bf((v1.z - m) * rs * w1.z + b1.z);
    o1.w = f2bf((v1.w - m) * rs * w1.w + b1.w);
    ((ushort4*)(lnb + (size_t)row * 2048))[tid] = o0;
    ((ushort4*)(lnb + (size_t)row * 2048))[256 + tid] = o1;
    return;
  }
  if (bid < 23552) {                           // ---- weight transposes ----
    int tb = bid - 20480;
    const float* src; unsigned short* dst; int Kd, N; const float* rsc; float sc;
    if (tb < 1024)      { src = Wq;   dst = WqT;   Kd = 2048; N = 512;  rsc = nullptr; sc = 0.125f; }
    else if (tb < 2048) { tb -= 1024; src = Wkv;  dst = WkvT;  Kd = 1024; N = 1024; rsc = nm_w;   sc = 1.0f; }
    else                { tb -= 2048; src = Wout; dst = WoutT; Kd = 512;  N = 2048; rsc = nullptr; sc = 1.0f; }
    float (*tile)[33] = (float(*)[33])smem;
    const int tx = tid & 31, ty = tid >> 5;
    const int ntiles = N >> 5;
    const int k0 = (tb / ntiles) << 5;
    const int n0 = (tb % ntiles) << 5;
    #pragma unroll
    for (int r = 0; r < 4; ++r) {
      const int kk = ty + r * 8;
      float v = src[(size_t)(k0 + kk) * N + n0 + tx] * sc;
      if (rsc) v *= rsc[k0 + kk];
      tile[kk][tx] = v;
    }
    __syncthreads();
    #pragma unroll
    for (int r = 0; r < 4; ++r) {
      const int nn = ty + r * 8;
      dst[(size_t)(n0 + nn) * Kd + k0 + tx] = f2bf(tile[tx][nn]);
    }
    return;
  }
  {                                            // ---- c1c2 partials ----
    const int cb = bid - 23552;
    const int kc = cb >> 2;
    const int n  = (cb & 3) * 256 + tid;
    float s1 = 0.f, s2 = 0.f;
    const int k0 = kc * 64;
    for (int k = k0; k < k0 + 64; ++k) {
      const float wv = Wkv[(size_t)k * 1024 + n];
      s1 += nm_w[k] * wv;
      s2 += nm_b[k] * wv;
    }
    part[(size_t)(kc * 2 + 0) * 1024 + n] = s1;
    part[(size_t)(kc * 2 + 1) * 1024 + n] = s2;
  }
}

__global__ __launch_bounds__(256) void k_c1c2_red(
    const float* __restrict__ part, float* __restrict__ c1, float* __restrict__ c2)
{
  const int n = blockIdx.x * 256 + threadIdx.x;
  float s1 = 0.f, s2 = 0.f;
  #pragma unroll
  for (int kc = 0; kc < 16; ++kc) {
    s1 += part[(size_t)(kc * 2 + 0) * 1024 + n];
    s2 += part[(size_t)(kc * 2 + 1) * 1024 + n];
  }
  c1[n] = s1; c2[n] = s2;
}

// =====================================================================================
// MERGED GEMM launch, 1152 blocks x 512 threads:
//  blocks [0,1024):    kv = LN(x)@Wkv^T, R6/R10 8-phase 256^2 structure VERBATIM
//                      (906 TF measured), own bijective XCD swizzle over 1024.
//  blocks [1024,1152): q = LN(lat)@(Wq/8)^T, [4096x512x2048], BM=64 BN=256, 8 waves,
//                      two-buffer stage-ahead __syncthreads structure (R10-measured
//                      better for small K-count), mod-8 rotation swizzle, 80KB LDS.
// Ranges are independent (both read only k_pre/c1c2 outputs; disjoint writes); q
// blocks dispatch last and fill CUs freed during kv's tail scheduling rounds.
// =====================================================================================
#define BAR8   __builtin_amdgcn_s_barrier()
#define GATE4  asm volatile("s_waitcnt vmcnt(4)\n\ts_barrier" ::: "memory")

__global__ __launch_bounds__(512, 2) void k_mm(
    const unsigned short* __restrict__ A,    // xb bf16 [65536][1024]
    const unsigned short* __restrict__ Bt,   // WkvT bf16 [1024][1024]
    unsigned short* __restrict__ C,          // kv bf16 [65536][1024]
    const float* __restrict__ mu, const float* __restrict__ rstd,
    const float* __restrict__ c1, const float* __restrict__ c2,
    const unsigned short* __restrict__ Aq,   // lnb bf16 [4096][2048]
    const unsigned short* __restrict__ Bq,   // WqT bf16 [512][2048]
    unsigned short* __restrict__ Cq)         // qbuf bf16 [4096][512]
{
  __shared__ __attribute__((aligned(16))) char lds[131072];
  const int tid = threadIdx.x;
  const int wid = tid >> 6, lane = tid & 63;
  const int g = lane >> 4, c = lane & 15;

  if (blockIdx.x < 1024) {
    // ------------------------------ kv: 8-phase 256^2 ------------------------------
    constexpr int NKT = 16;                   // K=1024 / BK=64
    int bid = blockIdx.x;
    bid = (bid & 7) * 128 + (bid >> 3);       // bijective XCD swizzle over 1024
    const int mt = bid >> 2, nt = bid & 3;    // nt fastest: 4 blocks share A panel
    const int wr = wid >> 2, wc = wid & 3;
    const int MO = wr * 128, NO = wc * 64;

    const unsigned short* gA = A + (size_t)mt * 256 * 1024;
    const unsigned short* gB = Bt + (size_t)nt * 256 * 1024;

    const f32x4 zz = {0.f, 0.f, 0.f, 0.f};
    f32x4 acc[8][4];
    #pragma unroll
    for (int m = 0; m < 8; ++m)
      #pragma unroll
      for (int n = 0; n < 4; ++n) acc[m][n] = zz;

    auto stageA = [&](int buf, int kk, int kt) {
      #pragma unroll
      for (int i = 0; i < 2; ++i) {
        const int o = (i * 512 + tid) * 16;
        const int row = o >> 6;
        const int ss = ((((o >> 4) & 3) - (row >> 1)) & 3);
        gload_lds16((const char*)(gA + (size_t)row * 1024 + kt * 64 + kk * 32) + ss * 16,
                    lds + buf * 32768 + kk * 16384 + o);
      }
    };
    auto stageB = [&](int buf, int kk, int kt) {
      #pragma unroll
      for (int i = 0; i < 2; ++i) {
        const int o = (i * 512 + tid) * 16;
        const int row = o >> 6;
        const int ss = ((((o >> 4) & 3) - (row >> 1)) & 3);
        gload_lds16((const char*)(gB + (size_t)row * 1024 + kt * 64 + kk * 32) + ss * 16,
                    lds + 65536 + buf * 32768 + kk * 16384 + o);
      }
    };
    auto rdA = [&](int buf, int kk, int m) -> bfrag8 {
      const int row = MO + m * 16 + c;
      return *(const bfrag8*)(lds + buf * 32768 + kk * 16384 + row * 64
                              + (((g + (row >> 1)) & 3) << 4));
    };
    auto rdB = [&](int buf, int kk, int n) -> bfrag8 {
      const int row = NO + n * 16 + c;
      return *(const bfrag8*)(lds + 65536 + buf * 32768 + kk * 16384 + row * 64
                              + (((g + (row >> 1)) & 3) << 4));
    };

    bfrag8 a[8], b0[4], b1[4];

    auto tile4 = [&](int buf, int sb, int ukt) {
      #pragma unroll
      for (int m = 0; m < 8; ++m) a[m] = rdA(buf, 0, m);
      #pragma unroll
      for (int n = 0; n < 4; ++n) b0[n] = rdB(buf, 0, n);
      stageA(sb, 0, ukt);
      __builtin_amdgcn_s_setprio(1);
      #pragma unroll
      for (int m = 0; m < 8; ++m) {
        acc[m][0] = __builtin_amdgcn_mfma_f32_16x16x32_bf16(a[m], b0[0], acc[m][0], 0, 0, 0);
        acc[m][1] = __builtin_amdgcn_mfma_f32_16x16x32_bf16(a[m], b0[1], acc[m][1], 0, 0, 0);
      }
      __builtin_amdgcn_s_setprio(0);
      GATE4;
      #pragma unroll
      for (int n = 0; n < 4; ++n) b1[n] = rdB(buf, 1, n);
      stageB(sb, 0, ukt);
      __builtin_amdgcn_s_setprio(1);
      #pragma unroll
      for (int m = 0; m < 8; ++m) {
        acc[m][2] = __builtin_amdgcn_mfma_f32_16x16x32_bf16(a[m], b0[2], acc[m][2], 0, 0, 0);
        acc[m][3] = __builtin_amdgcn_mfma_f32_16x16x32_bf16(a[m], b0[3], acc[m][3], 0, 0, 0);
      }
      __builtin_amdgcn_s_setprio(0);
      GATE4;
      #pragma unroll
      for (int m = 0; m < 8; ++m) a[m] = rdA(buf, 1, m);
      stageB(sb, 1, ukt);
      __builtin_amdgcn_s_setprio(1);
      #pragma unroll
      for (int m = 0; m < 8; ++m) {
        acc[m][0] = __builtin_amdgcn_mfma_f32_16x16x32_bf16(a[m], b1[0], acc[m][0], 0, 0, 0);
        acc[m][1] = __builtin_amdgcn_mfma_f32_16x16x32_bf16(a[m], b1[1], acc[m][1], 0, 0, 0);
      }
      __builtin_amdgcn_s_setprio(0);
      BAR8;
      stageA(sb, 1, ukt);
      __builtin_amdgcn_s_setprio(1);
      #pragma unroll
      for (int m = 0; m < 8; ++m) {
        acc[m][2] = __builtin_amdgcn_mfma_f32_16x16x32_bf16(a[m], b1[2], acc[m][2], 0, 0, 0);
        acc[m][3] = __builtin_amdgcn_mfma_f32_16x16x32_bf16(a[m], b1[3], acc[m][3], 0, 0, 0);
      }
      __builtin_amdgcn_s_setprio(0);
      GATE4;
    };

    stageA(0, 0, 0); stageB(0, 0, 0); stageB(0, 1, 0); stageA(0, 1, 0);
    GATE4;

    for (int t = 0; t < NKT; t += 2) {
      const int u2 = (t + 2 < NKT) ? t + 2 : 0;  // wrap dummy keeps vmcnt uniform
      tile4(0, 1, t + 1);
      tile4(1, 0, u2);
    }
    asm volatile("s_waitcnt vmcnt(0)" ::: "memory");

    // epilogue: kv = rstd*(acc - mu*c1) + c2 -> bf16
    #pragma unroll
    for (int m = 0; m < 8; ++m) {
      #pragma unroll
      for (int j = 0; j < 4; ++j) {
        const size_t orow = (size_t)mt * 256 + MO + m * 16 + g * 4 + j;
        const float rs = rstd[orow], muv = mu[orow];
        #pragma unroll
        for (int n = 0; n < 4; ++n) {
          const int gcol = nt * 256 + NO + n * 16 + c;
          const float v = rs * (acc[m][n][j] - muv * c1[gcol]) + c2[gcol];
          C[orow * 1024 + gcol] = f2bf(v);
        }
      }
    }
    return;
  }

  // ------------------------------ q: BM=64 BN=256, 2-buffer ------------------------
  {
    constexpr int BK = 64, MF = 4, NF = 2;
    int lb = blockIdx.x - 1024;                // 128 blocks
    lb = (lb & 7) * 16 + (lb >> 3);            // bijective XCD swizzle over 128
    const int mt = lb >> 1, nt = lb & 1;       // mtiles=64, ntiles=2
    const int NO = (wid & 7) * 32;             // 8 waves across N (WM=1)
    const int MO = 0;

    const unsigned short* gA = Aq + (size_t)mt * 64 * 2048;
    const unsigned short* gB = Bq + (size_t)nt * 256 * 2048;
    // LDS carve: As[2][64*64] @ 0 (16KB), Bs[2][256*64] @ 16384 (64KB)
    auto asb = [&](int buf) { return lds + buf * 8192; };
    auto bsb = [&](int buf) { return lds + 16384 + buf * 32768; };

    const f32x4 zz = {0.f, 0.f, 0.f, 0.f};
    f32x4 acc[MF][NF];
    #pragma unroll
    for (int m = 0; m < MF; ++m)
      #pragma unroll
      for (int n = 0; n < NF; ++n) acc[m][n] = zz;

    auto stage = [&](int buf, int kt) {
      {
        const int o = tid * 16;                // LA = 1
        const int row = o >> 7;
        const int sg = (((o >> 4) & 7) - row) & 7;
        gload_lds16((const char*)(gA + (size_t)row * 2048 + kt * BK) + sg * 16,
                    asb(buf) + o);
      }
      #pragma unroll
      for (int i = 0; i < 4; ++i) {            // LB = 4
        const int o = (i * 512 + tid) * 16;
        const int row = o >> 7;
        const int sg = (((o >> 4) & 7) - row) & 7;
        gload_lds16((const char*)(gB + (size_t)row * 2048 + kt * BK) + sg * 16,
                    bsb(buf) + o);
      }
    };
    auto compute = [&](int buf) {
      #pragma unroll
      for (int kk = 0; kk < 2; ++kk) {
        bfrag8 af[MF], bf[NF];
        #pragma unroll
        for (int m = 0; m < MF; ++m) {
          const int rw = MO + m * 16 + c;
          af[m] = *(const bfrag8*)((const char*)asb(buf) + rw * 128
                                   + (((kk * 4 + g + rw) & 7) << 4));
        }
        #pragma unroll
        for (int n = 0; n < NF; ++n) {
          const int rw = NO + n * 16 + c;
          bf[n] = *(const bfrag8*)((const char*)bsb(buf) + rw * 128
                                   + (((kk * 4 + g + rw) & 7) << 4));
        }
        #pragma unroll
        for (int m = 0; m < MF; ++m)
          #pragma unroll
          for (int n = 0; n < NF; ++n)
            acc[m][n] = __builtin_amdgcn_mfma_f32_16x16x32_bf16(af[m], bf[n], acc[m][n], 0, 0, 0);
      }
    };

    const int nkt = 2048 / BK;                 // 32
    stage(0, 0);
    __syncthreads();
    for (int t = 0; t < nkt; t += 2) {
      if (t + 1 < nkt) stage(1, t + 1);
      compute(0);
      __syncthreads();
      if (t + 2 < nkt) stage(0, t + 2);
      if (t + 1 < nkt) compute(1);
      __syncthreads();
    }

    #pragma unroll
    for (int m = 0; m < MF; ++m) {
      #pragma unroll
      for (int j = 0; j < 4; ++j) {
        const size_t orow = (size_t)mt * 64 + MO + m * 16 + g * 4 + j;
        #pragma unroll
        for (int n = 0; n < NF; ++n) {
          const int gcol = nt * 256 + NO + n * 16 + c;
          Cq[orow * 512 + gcol] = f2bf(acc[m][n][j]);
        }
      }
    }
  }
}

// =====================================================================================
// small GEMM (out): R2 two-buffer stage-ahead structure, BK=64, mod-8 rotation swizzle.
// MODE 2: plain -> f32
// =====================================================================================
template<int BM, int BN, int WM, int WN, int NT, int MODE>
__global__ __launch_bounds__(NT, 2) void k_gemm(
    const unsigned short* __restrict__ A, int lda,
    const unsigned short* __restrict__ Bt, int ldb,
    int K, int mtiles, int ntiles,
    void* __restrict__ Cout, int ldc)
{
  constexpr int BK = 64;
  constexpr int NW = NT / 64;
  constexpr int MF = (BM / WM) / 16;
  constexpr int NF = (BN / WN) / 16;
  constexpr int LA = (BM * BK) / (8 * NT);
  constexpr int LB = (BN * BK) / (8 * NT);
  static_assert(WM * WN == NW, "wave grid");
  static_assert(LA >= 1 && LB >= 1, "tile too small for NT");

  __shared__ __attribute__((aligned(16))) unsigned short As[2][BM * BK];
  __shared__ __attribute__((aligned(16))) unsigned short Bs[2][BN * BK];

  int bid = blockIdx.x;
  {
    const int nwg = gridDim.x;
    if ((nwg & 7) == 0) {
      const int q = nwg >> 3;
      bid = (bid & 7) * q + (bid >> 3);
    }
  }
  const int mt = bid / ntiles, nt = bid % ntiles;
  const int tid = threadIdx.x;
  const int wid = tid >> 6, lane = tid & 63;
  const int g = lane >> 4, c = lane & 15;
  const int wr = wid / WN, wc = wid % WN;
  const int MO = wr * (BM / WM), NO = wc * (BN / WN);

  const unsigned short* gA = A + (size_t)mt * BM * lda;
  const unsigned short* gB = Bt + (size_t)nt * BN * ldb;

  const f32x4 zz = {0.f, 0.f, 0.f, 0.f};
  f32x4 acc[MF][NF];
  #pragma unroll
  for (int m = 0; m < MF; ++m)
    #pragma unroll
    for (int n = 0; n < NF; ++n) acc[m][n] = zz;

  auto stage = [&](int buf, int kt) {
    #pragma unroll
    for (int i = 0; i < LA; ++i) {
      const int o = (i * NT + tid) * 16;
      const int row = o >> 7;                       // 128B rows
      const int sg = (((o >> 4) & 7) - row) & 7;    // pre-rotated source slot
      gload_lds16((const char*)(gA + (size_t)row * lda + kt * BK) + sg * 16,
                  (char*)&As[buf][0] + o);
    }
    #pragma unroll
    for (int i = 0; i < LB; ++i) {
      const int o = (i * NT + tid) * 16;
      const int row = o >> 7;
      const int sg = (((o >> 4) & 7) - row) & 7;
      gload_lds16((const char*)(gB + (size_t)row * ldb + kt * BK) + sg * 16,
                  (char*)&Bs[buf][0] + o);
    }
  };

  auto compute = [&](int buf) {
    #pragma unroll
    for (int kk = 0; kk < 2; ++kk) {
      bfrag8 af[MF], bf[NF];
      #pragma unroll
      for (int m = 0; m < MF; ++m) {
        const int rw = MO + m * 16 + c;
        af[m] = *(const bfrag8*)((const char*)&As[buf][0] + rw * 128
                                 + (((kk * 4 + g + rw) & 7) << 4));
      }
      #pragma unroll
      for (int n = 0; n < NF; ++n) {
        const int rw = NO + n * 16 + c;
        bf[n] = *(const bfrag8*)((const char*)&Bs[buf][0] + rw * 128
                                 + (((kk * 4 + g + rw) & 7) << 4));
      }
      #pragma unroll
      for (int m = 0; m < MF; ++m)
        #pragma unroll
        for (int n = 0; n < NF; ++n)
          acc[m][n] = __builtin_amdgcn_mfma_f32_16x16x32_bf16(af[m], bf[n], acc[m][n], 0, 0, 0);
    }
  };

  const int nkt = K / BK;
  stage(0, 0);
  __syncthreads();
  for (int t = 0; t < nkt; t += 2) {
    if (t + 1 < nkt) stage(1, t + 1);
    compute(0);
    __syncthreads();
    if (t + 2 < nkt) stage(0, t + 2);
    if (t + 1 < nkt) compute(1);
    __syncthreads();
  }

  #pragma unroll
  for (int m = 0; m < MF; ++m) {
    #pragma unroll
    for (int j = 0; j < 4; ++j) {
      const size_t orow = (size_t)mt * BM + MO + m * 16 + g * 4 + j;
      #pragma unroll
      for (int n = 0; n < NF; ++n) {
        const int gcol = nt * BN + NO + n * 16 + c;
        const float v = acc[m][n][j];
        if constexpr (MODE == 2) ((float*)Cout)[orow * ldc + gcol] = v;
        else ((unsigned short*)Cout)[orow * ldc + gcol] = f2bf(v);
      }
    }
  }
}

// ---------------- flash attention per (bt, head): 4 waves x 16 queries ----------------
__global__ __launch_bounds__(256) void k_attn(
    const unsigned short* __restrict__ q,   // [BT*64][512] bf16 (scale 1/8 pre-folded)
    const unsigned short* __restrict__ kv,  // [BT*1024][1024] bf16: k | v
    unsigned short* __restrict__ ao)        // [BT*64][512] bf16
{
  __shared__ __attribute__((aligned(16))) unsigned short Vt[64 * 64];  // [d][key] swizzled
  const int bid = blockIdx.x;
  const int bt = bid >> 3, h = bid & 7;
  const int tid = threadIdx.x;
  const int wid = tid >> 6, lane = tid & 63;
  const int g = lane >> 4, c = lane & 15;

  const size_t qoff = ((size_t)bt * 64 + wid * 16 + c) * 512 + h * 64;
  const bfrag8 qf0 = *(const bfrag8*)(q + qoff + g * 8);
  const bfrag8 qf1 = *(const bfrag8*)(q + qoff + 32 + g * 8);

  const f32x4 zz = {0.f, 0.f, 0.f, 0.f};
  f32x4 o[4] = {zz, zz, zz, zz};
  float m_run = -1e30f, l_run = 0.f;

  const size_t kvbase = (size_t)bt * 1024 * 1024;
  const unsigned short* kbase = kv + kvbase + h * 64;
  const unsigned short* vbase = kv + kvbase + 512 + h * 64;

  for (int ch = 0; ch < 16; ++ch) {            // 16 chunks of 64 keys
    #pragma unroll
    for (int rr = 0; rr < 2; ++rr) {           // stage V transposed + XOR-swizzled
      const int key = rr * 32 + (tid >> 3);
      const int d0 = (tid & 7) * 8;
      const bfrag8 vv = *(const bfrag8*)(vbase + (size_t)(ch * 64 + key) * 1024 + d0);
      #pragma unroll
      for (int j = 0; j < 8; ++j)
        Vt[(d0 + j) * 64 + (key ^ (j << 3))] = (unsigned short)vv[j];
    }
    __syncthreads();
    #pragma unroll
    for (int ks = 0; ks < 2; ++ks) {           // 2 x 32-key steps
      const int kb = ch * 64 + ks * 32;
      f32x4 s[2];
      #pragma unroll
      for (int t = 0; t < 2; ++t) {            // key permutation: row m -> key 8*(m>>2)+4t+(m&3)
        const int kr = ((c >> 2) << 3) + (t << 2) + (c & 3);
        const unsigned short* krow = kbase + (size_t)(kb + kr) * 1024;
        s[t] = zz;
        s[t] = __builtin_amdgcn_mfma_f32_16x16x32_bf16(*(const bfrag8*)(krow + g * 8),      qf0, s[t], 0, 0, 0);
        s[t] = __builtin_amdgcn_mfma_f32_16x16x32_bf16(*(const bfrag8*)(krow + 32 + g * 8), qf1, s[t], 0, 0, 0);
      }
      float pm = s[0][0];
      #pragma unroll
      for (int i = 1; i < 4; ++i) pm = fmaxf(pm, s[0][i]);
      #pragma unroll
      for (int i = 0; i < 4; ++i) pm = fmaxf(pm, s[1][i]);
      pm = fmaxf(pm, __shfl_xor(pm, 16));
      pm = fmaxf(pm, __shfl_xor(pm, 32));
      const float mn = fmaxf(m_run, pm);
      const float alpha = __expf(m_run - mn);
      float p[8];
      #pragma unroll
      for (int i = 0; i < 4; ++i) p[i]     = __expf(s[0][i] - mn);
      #pragma unroll
      for (int i = 0; i < 4; ++i) p[4 + i] = __expf(s[1][i] - mn);
      float ts = 0.f;
      #pragma unroll
      for (int i = 0; i < 8; ++i) ts += p[i];
      ts += __shfl_xor(ts, 16);
      ts += __shfl_xor(ts, 32);
      l_run = l_run * alpha + ts;
      m_run = mn;
      float ar[4];
      #pragma unroll
      for (int rj = 0; rj < 4; ++rj) ar[rj] = __shfl(alpha, g * 4 + rj);
      #pragma unroll
      for (int db = 0; db < 4; ++db)
        #pragma unroll
        for (int j = 0; j < 4; ++j) o[db][j] *= ar[j];
      bfrag8 pa;
      #pragma unroll
      for (int i = 0; i < 8; ++i) pa[i] = (short)f2bf(p[i]);
      #pragma unroll
      for (int db = 0; db < 4; ++db) {
        const int d = db * 16 + c;
        const bfrag8 vb = *(const bfrag8*)(Vt + d * 64 + ((ks * 32 + g * 8) ^ ((c & 7) << 3)));
        o[db] = __builtin_amdgcn_mfma_f32_16x16x32_bf16(pa, vb, o[db], 0, 0, 0);
      }
    }
    __syncthreads();
  }
  float lr[4];
  #pragma unroll
  for (int rj = 0; rj < 4; ++rj) lr[rj] = __shfl(l_run, g * 4 + rj);
  #pragma unroll
  for (int db = 0; db < 4; ++db)
    #pragma unroll
    for (int j = 0; j < 4; ++j) {
      const float val = o[db][j] / lr[j];
      ao[((size_t)bt * 64 + wid * 16 + g * 4 + j) * 512 + h * 64 + db * 16 + c] = f2bf(val);
    }
}

// --------------------------------- launch -------------------------------------------
extern "C" void kernel_launch(void* const* d_in, const int* in_sizes, int n_in,
                              void* d_out, int out_size, void* d_ws, size_t ws_size,
                              hipStream_t stream)
{
  const float* x    = (const float*)d_in[0];
  const float* lat  = (const float*)d_in[1];
  const float* nm_w = (const float*)d_in[2];
  const float* nm_b = (const float*)d_in[3];
  const float* nl_w = (const float*)d_in[4];
  const float* nl_b = (const float*)d_in[5];
  const float* Wq   = (const float*)d_in[6];
  const float* Wkv  = (const float*)d_in[7];
  const float* Wout = (const float*)d_in[8];

  char* p = (char*)d_ws;
  auto take = [&](size_t bytes) { char* r = p; p += (bytes + 255) & ~(size_t)255; return r; };
  unsigned short* xb    = (unsigned short*)take(64ull * 1024 * 1024 * 2);  // bf16(x)
  unsigned short* kvb   = (unsigned short*)take(64ull * 1024 * 1024 * 2);  // kv bf16
  unsigned short* lnb   = (unsigned short*)take(4096ull * 2048 * 2);       // LN(latents)
  unsigned short* qbuf  = (unsigned short*)take(4096ull * 512 * 2);        // q (scaled)
  unsigned short* aob   = (unsigned short*)take(4096ull * 512 * 2);        // attn out
  unsigned short* WqT   = (unsigned short*)take(512ull * 2048 * 2);
  unsigned short* WkvT  = (unsigned short*)take(1024ull * 1024 * 2);
  unsigned short* WoutT = (unsigned short*)take(2048ull * 512 * 2);
  float* muv  = (float*)take(65536ull * 4);
  float* rsd  = (float*)take(65536ull * 4);
  float* c1   = (float*)take(1024 * 4);
  float* c2   = (float*)take(1024 * 4);
  float* part = (float*)take(32ull * 1024 * 4);
  if ((size_t)(p - (char*)d_ws) > ws_size) return;  // insufficient workspace: fail loudly

  // all independent preprocessing in one launch
  k_pre<<<dim3(23616), 256, 0, stream>>>(x, xb, muv, rsd,
                                         lat, nl_w, nl_b, lnb,
                                         Wq, WqT, Wkv, WkvT, Wout, WoutT,
                                         nm_w, nm_b, part);
  k_c1c2_red<<<dim3(4), 256, 0, stream>>>(part, c1, c2);

  // kv GEMM (1024 blocks) + q GEMM (128 blocks) merged: independent ranges overlap
  k_mm<<<dim3(1152), 512, 0, stream>>>(xb, WkvT, kvb, muv, rsd, c1, c2,
                                       lnb, WqT, qbuf);

  k_attn<<<dim3(512), 256, 0, stream>>>(qbuf, kvb, aob);

  // out = attnout @ Wout: [4096 x 2048 x 512] -> f32
  k_gemm<64, 128, 1, 4, 256, 2><<<dim3(1024), 256, 0, stream>>>(
      aob, 512, WoutT, 512, 512, 64, 16, d_out, 2048);
}